// Round 1
// baseline (443.702 us; speedup 1.0000x reference)
//
#include <hip/hip_runtime.h>

typedef unsigned short u16t;
typedef __bf16 bf16x8 __attribute__((ext_vector_type(8)));
typedef float  f32x4  __attribute__((ext_vector_type(4)));

#define DEV __device__ __forceinline__

DEV u16t f32_to_bf16(float f) {
    unsigned u = __float_as_uint(f);
    unsigned r = (u + 0x7FFFu + ((u >> 16) & 1u)) >> 16;   // RNE
    return (u16t)r;
}

DEV float gelu_exact(float x) {
    return 0.5f * x * (1.0f + erff(x * 0.70710678118654752f));
}

// ---------------------------------------------------------------- LayerNorm
// one block (256 thr) per row of 768; output bf16
__global__ __launch_bounds__(256)
void ln_kernel(const float* __restrict__ x, const float* __restrict__ g,
               const float* __restrict__ b, u16t* __restrict__ out)
{
    const int row = blockIdx.x;
    const int t = threadIdx.x;
    const float* xr = x + (size_t)row * 768;
    float v0 = xr[t], v1 = xr[t + 256], v2 = xr[t + 512];
    float s = v0 + v1 + v2;
    float s2 = v0 * v0 + v1 * v1 + v2 * v2;
#pragma unroll
    for (int off = 32; off > 0; off >>= 1) {
        s  += __shfl_xor(s, off);
        s2 += __shfl_xor(s2, off);
    }
    __shared__ float sm[8];
    const int w = t >> 6;
    if ((t & 63) == 0) { sm[w] = s; sm[4 + w] = s2; }
    __syncthreads();
    s  = sm[0] + sm[1] + sm[2] + sm[3];
    s2 = sm[4] + sm[5] + sm[6] + sm[7];
    const float mu  = s * (1.0f / 768.0f);
    const float var = fmaxf(s2 * (1.0f / 768.0f) - mu * mu, 0.0f);
    const float rst = rsqrtf(var + 1e-5f);
    u16t* o = out + (size_t)row * 768;
    o[t]       = f32_to_bf16((v0 - mu) * rst * g[t]       + b[t]);
    o[t + 256] = f32_to_bf16((v1 - mu) * rst * g[t + 256] + b[t + 256]);
    o[t + 512] = f32_to_bf16((v2 - mu) * rst * g[t + 512] + b[t + 512]);
}

// ---------------------------------------------------- transpose f32 -> bf16
// in [R,C] f32 -> out [C,R] bf16. Grid (C/64, R/64), block 256.
__global__ __launch_bounds__(256)
void transpose_cast(const float* __restrict__ in, u16t* __restrict__ out,
                    int R, int C)
{
    __shared__ float tile[64][65];
    const int c0 = blockIdx.x * 64, r0 = blockIdx.y * 64;
    const int t = threadIdx.x;
#pragma unroll
    for (int j = 0; j < 16; ++j) {
        const int idx = j * 256 + t;
        const int rl = idx >> 6, cl = idx & 63;
        tile[rl][cl] = in[(size_t)(r0 + rl) * C + c0 + cl];
    }
    __syncthreads();
#pragma unroll
    for (int j = 0; j < 16; ++j) {
        const int idx = j * 256 + t;
        const int cl = idx >> 6, rl = idx & 63;
        out[(size_t)(c0 + cl) * R + r0 + rl] = f32_to_bf16(tile[rl][cl]);
    }
}

// ------------------------------------------------------------------- GEMM
// C[M,N] = A[M,K](bf16) * BT[N,K]^T(bf16)   (BT row-major in K)
// MODE 0: store f32.  MODE 1: +res (+bias if non-null), store f32.
// MODE 2: gelu(acc + bias), store bf16.
// 128x128 tile, BK=64, 4 waves each 64x64 (4x4 frags of 16x16x32 MFMA).
template <int MODE>
__global__ __launch_bounds__(256)
void gemm_kernel(const u16t* __restrict__ A, const u16t* __restrict__ BT,
                 float* __restrict__ Cf, u16t* __restrict__ Cb,
                 const float* __restrict__ bias, const float* __restrict__ res,
                 int M, int Nn, int K)
{
    __shared__ u16t Asm[128 * 64];
    __shared__ u16t Bsm[128 * 64];
    const int t = threadIdx.x;
    const int w = t >> 6, lane = t & 63;
    const int l16 = lane & 15, lhi = lane >> 4;
    const int wr = w >> 1, wc = w & 1;
    const int m0 = blockIdx.x * 128, n0 = blockIdx.y * 128;

    const f32x4 fz = {0.f, 0.f, 0.f, 0.f};
    f32x4 acc[4][4];
#pragma unroll
    for (int i = 0; i < 4; ++i)
#pragma unroll
        for (int j = 0; j < 4; ++j) acc[i][j] = fz;

    const int rowA = lane >> 3;          // 0..7 within an 8-row segment
    const int colb = (lane & 7) * 16;    // byte offset within 128B LDS row

    for (int kt = 0; kt < K; kt += 64) {
        // stage A,B tiles: 16 KB each, 4 waves x 4 segs of 1KB
#pragma unroll
        for (int i = 0; i < 4; ++i) {
            const int seg = w * 4 + i;
            const char* ga = (const char*)A +
                ((size_t)(m0 + seg * 8 + rowA) * K + kt) * 2 + colb;
            __builtin_amdgcn_global_load_lds(
                (const __attribute__((address_space(1))) void*)ga,
                (__attribute__((address_space(3))) void*)((char*)Asm + seg * 1024),
                16, 0, 0);
            const char* gb = (const char*)BT +
                ((size_t)(n0 + seg * 8 + rowA) * K + kt) * 2 + colb;
            __builtin_amdgcn_global_load_lds(
                (const __attribute__((address_space(1))) void*)gb,
                (__attribute__((address_space(3))) void*)((char*)Bsm + seg * 1024),
                16, 0, 0);
        }
        __syncthreads();
#pragma unroll
        for (int kk = 0; kk < 64; kk += 32) {
            bf16x8 af[4], bfv[4];
#pragma unroll
            for (int i = 0; i < 4; ++i)
                af[i] = *reinterpret_cast<const bf16x8*>(
                    Asm + (64 * wr + 16 * i + l16) * 64 + kk + 8 * lhi);
#pragma unroll
            for (int j = 0; j < 4; ++j)
                bfv[j] = *reinterpret_cast<const bf16x8*>(
                    Bsm + (64 * wc + 16 * j + l16) * 64 + kk + 8 * lhi);
#pragma unroll
            for (int i = 0; i < 4; ++i)
#pragma unroll
                for (int j = 0; j < 4; ++j)
                    acc[i][j] = __builtin_amdgcn_mfma_f32_16x16x32_bf16(
                        af[i], bfv[j], acc[i][j], 0, 0, 0);
        }
        __syncthreads();
    }

    const int rb = m0 + 64 * wr + 4 * lhi;
    const int cb = n0 + 64 * wc + l16;
#pragma unroll
    for (int i = 0; i < 4; ++i) {
#pragma unroll
        for (int j = 0; j < 4; ++j) {
#pragma unroll
            for (int r = 0; r < 4; ++r) {
                const int row = rb + 16 * i + r;
                const int col = cb + 16 * j;
                float v = acc[i][j][r];
                if (MODE == 0) {
                    Cf[(size_t)row * Nn + col] = v;
                } else if (MODE == 1) {
                    v += res[(size_t)row * Nn + col];
                    if (bias) v += bias[col];
                    Cf[(size_t)row * Nn + col] = v;
                } else {
                    v = gelu_exact(v + bias[col]);
                    Cb[(size_t)row * Nn + col] = f32_to_bf16(v);
                }
            }
        }
    }
}

// ------------------------------------------------- qkv split / cast / V^T
// qkv f32 [B,N,3,H,64] -> Q,K bf16 [B*H, N, 64], VT bf16 [B*H, 64, N]
// grid (N/64, B*H), block 256
__global__ __launch_bounds__(256)
void split_qkv(const float* __restrict__ qkv, u16t* __restrict__ Q,
               u16t* __restrict__ K, u16t* __restrict__ VT)
{
    const int bh = blockIdx.y;
    const int b = bh / 12, h = bh % 12;
    const int n0 = blockIdx.x * 64;
    const int t = threadIdx.x;
    __shared__ float tile[64][65];
#pragma unroll
    for (int j = 0; j < 16; ++j) {
        const int idx = j * 256 + t;
        const int nl = idx >> 6, d = idx & 63;
        const size_t src = ((size_t)(b * 2048 + n0 + nl) * 36 + h) * 64 + d;
        const size_t dst = ((size_t)bh * 2048 + n0 + nl) * 64 + d;
        Q[dst] = f32_to_bf16(qkv[src]);          // qi = 0
        K[dst] = f32_to_bf16(qkv[src + 768]);    // qi = 1
        tile[nl][d] = qkv[src + 1536];           // qi = 2 (V)
    }
    __syncthreads();
#pragma unroll
    for (int j = 0; j < 16; ++j) {
        const int idx = j * 256 + t;
        const int d = idx >> 6, nl = idx & 63;
        VT[((size_t)bh * 64 + d) * 2048 + n0 + nl] = f32_to_bf16(tile[nl][d]);
    }
}

// ------------------------------------------------------- flash attention
// softmax(Q K^T * scale + bias) @ V, online softmax.
// grid (N/64, B*H), block 256 (4 waves, 16 q-rows each)
__global__ __launch_bounds__(256)
void attn_kernel(const u16t* __restrict__ Q, const u16t* __restrict__ K,
                 const u16t* __restrict__ VT, const float* __restrict__ bias,
                 u16t* __restrict__ out)
{
    const int SEQ = 2048;
    const int bh = blockIdx.y;
    const int b = bh / 12, h = bh % 12;
    const int q0 = blockIdx.x * 64;
    const int t = threadIdx.x;
    const int w = t >> 6, lane = t & 63;
    const int l16 = lane & 15, lhi = lane >> 4;

    __shared__ u16t p_lds[4][16][64];

    // Q A-fragments (row = l16, k(=d) = 8*lhi + 32*s), held in regs
    const u16t* qp = Q + ((size_t)bh * SEQ + q0 + 16 * w + l16) * 64 + 8 * lhi;
    const bf16x8 aq0 = *reinterpret_cast<const bf16x8*>(qp);
    const bf16x8 aq1 = *reinterpret_cast<const bf16x8*>(qp + 32);

    const f32x4 fz = {0.f, 0.f, 0.f, 0.f};
    float mrun[4], lrun[4];
    f32x4 acco[4];
#pragma unroll
    for (int r = 0; r < 4; ++r) { mrun[r] = -1e30f; lrun[r] = 0.f; }
#pragma unroll
    for (int df = 0; df < 4; ++df) acco[df] = fz;

    const size_t krow = (size_t)bh * SEQ;
    const float* brow = bias + ((size_t)h * SEQ + q0 + 16 * w + 4 * lhi) * SEQ;

    for (int k0 = 0; k0 < SEQ; k0 += 64) {
        // S = Q K^T  (4 kk-fragments of 16 cols, K-dim = d = 64)
        f32x4 s[4];
#pragma unroll
        for (int kkf = 0; kkf < 4; ++kkf) {
            const u16t* kp = K + (krow + k0 + 16 * kkf + l16) * 64 + 8 * lhi;
            bf16x8 bk0 = *reinterpret_cast<const bf16x8*>(kp);
            bf16x8 bk1 = *reinterpret_cast<const bf16x8*>(kp + 32);
            f32x4 z = fz;
            z = __builtin_amdgcn_mfma_f32_16x16x32_bf16(aq0, bk0, z, 0, 0, 0);
            z = __builtin_amdgcn_mfma_f32_16x16x32_bf16(aq1, bk1, z, 0, 0, 0);
            s[kkf] = z;
        }
        // online softmax per q-row (rows = 4*lhi + r, cols = 16*kkf + l16)
        float p[4][4];
#pragma unroll
        for (int r = 0; r < 4; ++r) {
            float mx = -1e30f;
#pragma unroll
            for (int kkf = 0; kkf < 4; ++kkf) {
                float v = s[kkf][r] * 0.125f +
                          brow[(size_t)r * SEQ + k0 + 16 * kkf + l16];
                p[kkf][r] = v;
                mx = fmaxf(mx, v);
            }
#pragma unroll
            for (int off = 8; off > 0; off >>= 1)
                mx = fmaxf(mx, __shfl_xor(mx, off));
            const float mn = fmaxf(mrun[r], mx);
            const float alpha = __expf(mrun[r] - mn);
            float rs = 0.f;
#pragma unroll
            for (int kkf = 0; kkf < 4; ++kkf) {
                float e = __expf(p[kkf][r] - mn);
                p[kkf][r] = e;
                rs += e;
            }
#pragma unroll
            for (int off = 8; off > 0; off >>= 1)
                rs += __shfl_xor(rs, off);
            lrun[r] = lrun[r] * alpha + rs;
            mrun[r] = mn;
#pragma unroll
            for (int df = 0; df < 4; ++df) acco[df][r] *= alpha;
        }
        // P -> LDS (bf16), per-wave region; same-wave RAW is in-order
#pragma unroll
        for (int kkf = 0; kkf < 4; ++kkf)
#pragma unroll
            for (int r = 0; r < 4; ++r)
                p_lds[w][4 * lhi + r][16 * kkf + l16] = f32_to_bf16(p[kkf][r]);
        // O += P @ V   (A = P rows=q, k=kk; B = V^T rows contiguous in n)
#pragma unroll
        for (int ss = 0; ss < 2; ++ss) {
            bf16x8 pa = *reinterpret_cast<const bf16x8*>(
                &p_lds[w][l16][32 * ss + 8 * lhi]);
#pragma unroll
            for (int df = 0; df < 4; ++df) {
                const u16t* vp = VT + ((size_t)bh * 64 + df * 16 + l16) * SEQ +
                                 k0 + 32 * ss + 8 * lhi;
                bf16x8 bv = *reinterpret_cast<const bf16x8*>(vp);
                acco[df] = __builtin_amdgcn_mfma_f32_16x16x32_bf16(
                    pa, bv, acco[df], 0, 0, 0);
            }
        }
    }
    // epilogue: O /= l, write bf16 [B,N,H*64]
#pragma unroll
    for (int df = 0; df < 4; ++df) {
#pragma unroll
        for (int r = 0; r < 4; ++r) {
            float v = acco[df][r] / lrun[r];
            out[((size_t)b * SEQ + q0 + 16 * w + 4 * lhi + r) * 768 +
                h * 64 + df * 16 + l16] = f32_to_bf16(v);
        }
    }
}

// ------------------------------------------------------------------ launch
extern "C" void kernel_launch(void* const* d_in, const int* in_sizes, int n_in,
                              void* d_out, int out_size, void* d_ws, size_t ws_size,
                              hipStream_t stream)
{
    const float* x    = (const float*)d_in[0];
    const float* Wqkv = (const float*)d_in[1];
    const float* Wout = (const float*)d_in[2];
    const float* g1   = (const float*)d_in[3];
    const float* be1  = (const float*)d_in[4];
    const float* g2   = (const float*)d_in[5];
    const float* be2  = (const float*)d_in[6];
    const float* W1   = (const float*)d_in[7];
    const float* b1   = (const float*)d_in[8];
    const float* W2   = (const float*)d_in[9];
    const float* b2   = (const float*)d_in[10];
    const float* ab   = (const float*)d_in[11];
    float* outp = (float*)d_out;

    char* ws = (char*)d_ws;
    size_t off = 0;
    auto alloc = [&](size_t bytes) -> char* {
        char* p = ws + off;
        off += (bytes + 255) & ~(size_t)255;
        return p;
    };

    u16t* WqkvT = (u16t*)alloc((size_t)2304 * 768 * 2);
    u16t* WoutT = (u16t*)alloc((size_t)768 * 768 * 2);
    u16t* W1T   = (u16t*)alloc((size_t)3072 * 768 * 2);
    u16t* W2T   = (u16t*)alloc((size_t)768 * 3072 * 2);
    u16t* h1    = (u16t*)alloc((size_t)4096 * 768 * 2);
    float* qkv  = (float*)alloc((size_t)4096 * 2304 * 4);  // reused as `act`
    u16t* Qb    = (u16t*)alloc((size_t)24 * 2048 * 64 * 2);
    u16t* Kb    = (u16t*)alloc((size_t)24 * 2048 * 64 * 2);
    u16t* VTb   = (u16t*)alloc((size_t)24 * 64 * 2048 * 2);
    u16t* attnb = (u16t*)alloc((size_t)4096 * 768 * 2);
    float* x1   = (float*)alloc((size_t)4096 * 768 * 4);
    u16t* h2    = (u16t*)alloc((size_t)4096 * 768 * 2);
    u16t* act   = (u16t*)qkv;   // qkv (37.7MB) dead after split; act needs 25.2MB

    // weight prep
    transpose_cast<<<dim3(36, 12), 256, 0, stream>>>(Wqkv, WqkvT, 768, 2304);
    transpose_cast<<<dim3(12, 12), 256, 0, stream>>>(Wout, WoutT, 768, 768);
    transpose_cast<<<dim3(48, 12), 256, 0, stream>>>(W1,   W1T,   768, 3072);
    transpose_cast<<<dim3(12, 48), 256, 0, stream>>>(W2,   W2T,   3072, 768);

    // attention block
    ln_kernel<<<4096, 256, 0, stream>>>(x, g1, be1, h1);
    gemm_kernel<0><<<dim3(32, 18), 256, 0, stream>>>(
        h1, WqkvT, qkv, nullptr, nullptr, nullptr, 4096, 2304, 768);
    split_qkv<<<dim3(32, 24), 256, 0, stream>>>(qkv, Qb, Kb, VTb);
    attn_kernel<<<dim3(32, 24), 256, 0, stream>>>(Qb, Kb, VTb, ab, attnb);
    gemm_kernel<1><<<dim3(32, 6), 256, 0, stream>>>(
        attnb, WoutT, x1, nullptr, nullptr, x, 4096, 768, 768);

    // feed-forward block
    ln_kernel<<<4096, 256, 0, stream>>>(x1, g2, be2, h2);
    gemm_kernel<2><<<dim3(32, 24), 256, 0, stream>>>(
        h2, W1T, nullptr, act, b1, nullptr, 4096, 3072, 768);
    gemm_kernel<1><<<dim3(32, 6), 256, 0, stream>>>(
        act, W2T, outp, nullptr, b2, x1, 4096, 768, 3072);
}